// Round 7
// baseline (332.019 us; speedup 1.0000x reference)
//
#include <hip/hip_runtime.h>

#define HW 3136          // 56*56
#define NPIX 25088       // 8*3136
#define NBLK 392         // NPIX/64

// workspace float offsets
#define OFF_Y1   0u
#define OFF_TR   1605632u
#define OFF_WT   2007040u      // w1t (16384) + w3t (16384)
#define OFF_OUT2 6924288u
#define OFF_Y3   8529920u
#define OFF_ST   14952448u
// stats sub-offsets (floats, relative to st base). acc: [C]=sum, [C..2C)=sumsq
#define ACC1 0
#define ACCR 128
#define ACC2 160
#define ACC3 288
#define FIN1 800
#define FINR 928
#define FIN2 960
#define FIN3 1088

__device__ __forceinline__ float wave_sum(float v) {
    #pragma unroll
    for (int off = 32; off > 0; off >>= 1) v += __shfl_xor(v, off, 64);
    return v;
}

// ---- K0: transpose weights w1[64][256]->w1t[256][64], w3[256][64]->w3t[64][256]
__global__ __launch_bounds__(256) void k_wt(const float* __restrict__ w1,
        const float* __restrict__ w3, float* __restrict__ w1t, float* __restrict__ w3t) {
    int i = blockIdx.x * 256 + threadIdx.x;
    if (i < 16384) {
        int oc = i >> 8, ic = i & 255;
        w1t[ic * 64 + oc] = w1[i];
    } else {
        int j = i - 16384;
        int oc = j >> 6, ic = j & 63;
        w3t[ic * 256 + oc] = w3[j];
    }
}

// ---- K1: conv1x1 256->64 + stats -------------------------------------------
// LDS-staged, software-pipelined K-chunks: prefetch cc+1 to regs during compute
// of cc. 128-thread blocks, 32-pix tiles (grid 784), 4x4 thread tile.
__global__ __launch_bounds__(128, 4) void k_conv1(const float* __restrict__ x,
        const float* __restrict__ w1t, float* __restrict__ y1, float* __restrict__ st) {
    __shared__ float xs[64][32];    // [ic-chunk][pix]  8KB
    __shared__ float ws[64][64];    // [ic-chunk][oc]  16KB
    int t = threadIdx.x, pb = blockIdx.x;
    int b = pb / 98, hw0 = (pb % 98) * 32;
    int tx = t & 7, ty = t >> 3;    // pix group (4 pix) / oc quad
    const size_t xbase = (size_t)(b * 256) * HW + hw0;

    float4 px[4], pw[8];
    #pragma unroll
    for (int i = 0; i < 4; i++) {
        int e = i * 128 + t, ic = e >> 3, p4 = e & 7;
        px[i] = *(const float4*)&x[xbase + (size_t)ic * HW + p4 * 4];
    }
    #pragma unroll
    for (int i = 0; i < 8; i++) {
        int e = i * 128 + t, ic = e >> 4, q = e & 15;
        pw[i] = *(const float4*)&w1t[ic * 64 + q * 4];
    }

    float acc[4][4];
    #pragma unroll
    for (int i = 0; i < 4; i++)
        #pragma unroll
        for (int j = 0; j < 4; j++) acc[i][j] = 0.f;

    #pragma unroll 1
    for (int cc = 0; cc < 4; cc++) {
        #pragma unroll
        for (int i = 0; i < 4; i++) {
            int e = i * 128 + t, ic = e >> 3, p4 = e & 7;
            *(float4*)&xs[ic][p4 * 4] = px[i];
        }
        #pragma unroll
        for (int i = 0; i < 8; i++) {
            int e = i * 128 + t, ic = e >> 4, q = e & 15;
            *(float4*)&ws[ic][q * 4] = pw[i];
        }
        __syncthreads();
        if (cc < 3) {   // prefetch next chunk; drains at the post-compute barrier
            #pragma unroll
            for (int i = 0; i < 4; i++) {
                int e = i * 128 + t, ic = e >> 3, p4 = e & 7;
                px[i] = *(const float4*)&x[xbase + (size_t)((cc + 1) * 64 + ic) * HW + p4 * 4];
            }
            #pragma unroll
            for (int i = 0; i < 8; i++) {
                int e = i * 128 + t, ic = e >> 4, q = e & 15;
                pw[i] = *(const float4*)&w1t[((cc + 1) * 64 + ic) * 64 + q * 4];
            }
        }
        #pragma unroll 8
        for (int c = 0; c < 64; c++) {
            float4 xv = *(const float4*)&xs[c][tx * 4];
            float4 wv = *(const float4*)&ws[c][ty * 4];
            float xa[4] = {xv.x, xv.y, xv.z, xv.w};
            float wa[4] = {wv.x, wv.y, wv.z, wv.w};
            #pragma unroll
            for (int i = 0; i < 4; i++)
                #pragma unroll
                for (int j = 0; j < 4; j++) acc[i][j] = fmaf(wa[i], xa[j], acc[i][j]);
        }
        __syncthreads();
    }
    #pragma unroll
    for (int i = 0; i < 4; i++) {
        int oc = ty * 4 + i;
        float4 o = make_float4(acc[i][0], acc[i][1], acc[i][2], acc[i][3]);
        *(float4*)&y1[((b * 64) + oc) * HW + hw0 + tx * 4] = o;
        float s = o.x + o.y + o.z + o.w;
        float q = o.x * o.x + o.y * o.y + o.z * o.z + o.w * o.w;
        #pragma unroll
        for (int off = 1; off <= 4; off <<= 1) {   // reduce over 8 tx lanes
            s += __shfl_xor(s, off, 64);
            q += __shfl_xor(q, off, 64);
        }
        if (tx == 0) {
            atomicAdd(&st[ACC1 + oc], s);
            atomicAdd(&st[ACC1 + 64 + oc], q);
        }
    }
}

// ---- finalize BN stats -> per-channel affine (a,b) -------------------------
__global__ void k_fin(const float* __restrict__ acc, float* __restrict__ fin,
                      const float* __restrict__ gamma, const float* __restrict__ beta, int C) {
    int c = threadIdx.x;
    if (c < C) {
        float mean = acc[c] * (1.0f / (float)NPIX);
        float var  = acc[C + c] * (1.0f / (float)NPIX) - mean * mean;
        float rstd = rsqrtf(var + 1e-5f);
        float a = gamma[c] * rstd;
        fin[c] = a;
        fin[C + c] = beta[c] - mean * a;
    }
}

// ---- K3: apply BN1+ReLU in-place, conv 64->16 + stats ----------------------
__global__ __launch_bounds__(256, 4) void k_bn1_convr(float* __restrict__ y1,
        const float* __restrict__ wr, float* __restrict__ tr, float* __restrict__ st) {
    __shared__ float ys[64][64];    // [ic][pix], BN1+ReLU applied
    __shared__ float wsh[16][64];   // [oc][ic]
    int t = threadIdx.x, pb = blockIdx.x;
    int b = pb / 49, hw0 = (pb % 49) * 64;
    int tx = t & 15, ty = t >> 4;   // pix group (4 pix) / oc (one of 16)
    #pragma unroll
    for (int i = 0; i < 16; i++) {
        int e = i * 256 + t, c = e >> 6, p = e & 63;
        int gi = ((b * 64) + c) * HW + hw0 + p;
        float v = y1[gi];
        v = fmaxf(st[FIN1 + c] * v + st[FIN1 + 64 + c], 0.f);
        ys[c][p] = v;
        y1[gi] = v;                 // y1 becomes y1r
    }
    #pragma unroll
    for (int i = 0; i < 4; i++) {
        int e = i * 256 + t;
        wsh[e >> 6][e & 63] = wr[e];
    }
    __syncthreads();
    float a0 = 0.f, a1 = 0.f, a2 = 0.f, a3 = 0.f;
    #pragma unroll 8
    for (int c = 0; c < 64; c++) {
        float4 yv = *(const float4*)&ys[c][tx * 4];
        float wv = wsh[ty][c];
        a0 = fmaf(wv, yv.x, a0); a1 = fmaf(wv, yv.y, a1);
        a2 = fmaf(wv, yv.z, a2); a3 = fmaf(wv, yv.w, a3);
    }
    *(float4*)&tr[((b * 16) + ty) * HW + hw0 + tx * 4] = make_float4(a0, a1, a2, a3);
    float s = a0 + a1 + a2 + a3;
    float q = a0 * a0 + a1 * a1 + a2 * a2 + a3 * a3;
    #pragma unroll
    for (int off = 1; off <= 8; off <<= 1) {
        s += __shfl_xor(s, off, 64);
        q += __shfl_xor(q, off, 64);
    }
    if (tx == 0) {
        atomicAdd(&st[ACCR + ty], s);
        atomicAdd(&st[ACCR + 16 + ty], q);
    }
}

// ---- K6: fused BNr+ReLU -> span conv (kernels in regs) -> involution + stats
// Split: each block handles 8 of the group's 16 channels (grid x2, LDS ~39KB).
__global__ __launch_bounds__(256) void k_invol(const float* __restrict__ y1r,
        const float* __restrict__ tr, const float* __restrict__ wsp,
        float* __restrict__ out2, float* __restrict__ st) {
    __shared__ float ts[16][256];      // BNr+ReLU'd tr tile (224 used)
    __shared__ float sw[49][16];       // span weights for this group
    __shared__ float ps[8][10][64];    // y1r halo tile (8 channels)
    __shared__ float red[4][16];
    int t = threadIdx.x, bidx = blockIdx.x;     // (((b*4+g)*14 + ht)*2 + h)
    int h = bidx & 1, r2 = bidx >> 1;
    int ht = r2 % 14;
    int bg = r2 / 14;
    int g = bg & 3, b = bg >> 2;
    int h0 = ht * 4;
    int c0 = h * 8;                    // channel offset within group
    // stage ts (BNr+ReLU applied) — all 16 channels (needed for kernel gen)
    #pragma unroll
    for (int i = 0; i < 16; i++) {
        int e = i * 256 + t, c = e >> 8, p = e & 255;
        if (p < 224) {
            float v = tr[((b * 16) + c) * HW + h0 * 56 + p];
            ts[c][p] = fmaxf(st[FINR + c] * v + st[FINR + 16 + c], 0.f);
        }
    }
    // stage span weights (group g): contiguous 784 floats
    for (int e = t; e < 784; e += 256) sw[e >> 4][e & 15] = wsp[g * 784 + e];
    // stage y1r halo for this block's 8 channels
    for (int i = 0; i < 20; i++) {
        int e = i * 256 + t;
        int c = e / 640, rem = e - c * 640;
        int r = rem >> 6, wc = rem & 63;
        int gh = h0 + r - 3, gw = wc - 3;
        float v = 0.f;
        if (gh >= 0 && gh < 56 && gw >= 0 && gw < 56)
            v = y1r[((b * 64) + g * 16 + c0 + c) * HW + gh * 56 + gw];
        ps[c][r][wc] = v;
    }
    __syncthreads();
    float accv[8];
    #pragma unroll
    for (int c = 0; c < 8; c++) accv[c] = 0.f;
    bool active = t < 224;
    if (active) {
        int lh = t / 56, lw = t % 56;
        // per-pixel kernel generation into registers (uses all 16 channels)
        float tsr[16];
        #pragma unroll
        for (int c = 0; c < 16; c++) tsr[c] = ts[c][t];
        float kr[49];
        #pragma unroll
        for (int k = 0; k < 49; k++) {
            const float4* swr = (const float4*)&sw[k][0];
            float4 u0 = swr[0], u1 = swr[1], u2 = swr[2], u3 = swr[3];
            float v = u0.x * tsr[0];
            v = fmaf(u0.y, tsr[1], v);  v = fmaf(u0.z, tsr[2], v);  v = fmaf(u0.w, tsr[3], v);
            v = fmaf(u1.x, tsr[4], v);  v = fmaf(u1.y, tsr[5], v);  v = fmaf(u1.z, tsr[6], v);
            v = fmaf(u1.w, tsr[7], v);  v = fmaf(u2.x, tsr[8], v);  v = fmaf(u2.y, tsr[9], v);
            v = fmaf(u2.z, tsr[10], v); v = fmaf(u2.w, tsr[11], v); v = fmaf(u3.x, tsr[12], v);
            v = fmaf(u3.y, tsr[13], v); v = fmaf(u3.z, tsr[14], v); v = fmaf(u3.w, tsr[15], v);
            kr[k] = v;
        }
        // involution MAC over this block's 8 channels
        #pragma unroll
        for (int k = 0; k < 49; k++) {
            int ki = k / 7, kj = k % 7;
            float kv = kr[k];
            #pragma unroll
            for (int c = 0; c < 8; c++)
                accv[c] = fmaf(kv, ps[c][lh + ki][lw + kj], accv[c]);
        }
        int hw = h0 * 56 + t;
        #pragma unroll
        for (int c = 0; c < 8; c++)
            out2[((b * 64) + g * 16 + c0 + c) * HW + hw] = accv[c];
    }
    int wave = t >> 6, lane = t & 63;
    #pragma unroll
    for (int c = 0; c < 8; c++) {
        float v = active ? accv[c] : 0.f;
        float s  = wave_sum(v);
        float s2 = wave_sum(v * v);
        if (lane == 0) { red[wave][c] = s; red[wave][8 + c] = s2; }
    }
    __syncthreads();
    if (t < 16) {
        float s = red[0][t] + red[1][t] + red[2][t] + red[3][t];
        int c = t & 7, isq = t >> 3;
        atomicAdd(&st[ACC2 + isq * 64 + g * 16 + c0 + c], s);
    }
}

// ---- K7: apply BN2+ReLU, conv 64->256 + stats ------------------------------
// occ chunk on grid (blockIdx & 3): one staging + one inner loop per block.
__global__ __launch_bounds__(256, 4) void k_bn2_conv3(const float* __restrict__ out2,
        const float* __restrict__ w3t, float* __restrict__ y3, float* __restrict__ st) {
    __shared__ float os[64][64];    // [ic][pix], BN2+ReLU applied
    __shared__ float wst[64][64];   // [ic][oc-chunk]
    int t = threadIdx.x, blk = blockIdx.x;
    int occ = blk & 3, pb = blk >> 2;
    int b = pb / 49, hw0 = (pb % 49) * 64;
    int tx = t & 15, ty = t >> 4;
    #pragma unroll
    for (int i = 0; i < 16; i++) {
        int e = i * 256 + t, c = e >> 6, p = e & 63;
        float v = out2[((b * 64) + c) * HW + hw0 + p];
        os[c][p] = fmaxf(st[FIN2 + c] * v + st[FIN2 + 64 + c], 0.f);
        wst[c][p] = w3t[c * 256 + occ * 64 + p];
    }
    __syncthreads();
    float acc[4][4];
    #pragma unroll
    for (int i = 0; i < 4; i++)
        #pragma unroll
        for (int j = 0; j < 4; j++) acc[i][j] = 0.f;
    #pragma unroll 8
    for (int c = 0; c < 64; c++) {
        float4 xv = *(const float4*)&os[c][tx * 4];
        float4 wv = *(const float4*)&wst[c][ty * 4];
        float xa[4] = {xv.x, xv.y, xv.z, xv.w};
        float wa[4] = {wv.x, wv.y, wv.z, wv.w};
        #pragma unroll
        for (int i = 0; i < 4; i++)
            #pragma unroll
            for (int j = 0; j < 4; j++) acc[i][j] = fmaf(wa[i], xa[j], acc[i][j]);
    }
    #pragma unroll
    for (int i = 0; i < 4; i++) {
        int oc = occ * 64 + ty * 4 + i;
        float4 o = make_float4(acc[i][0], acc[i][1], acc[i][2], acc[i][3]);
        *(float4*)&y3[((b * 256) + oc) * HW + hw0 + tx * 4] = o;
        float s = o.x + o.y + o.z + o.w;
        float q = o.x * o.x + o.y * o.y + o.z * o.z + o.w * o.w;
        #pragma unroll
        for (int off = 1; off <= 8; off <<= 1) {
            s += __shfl_xor(s, off, 64);
            q += __shfl_xor(q, off, 64);
        }
        if (tx == 0) {
            atomicAdd(&st[ACC3 + oc], s);
            atomicAdd(&st[ACC3 + 256 + oc], q);
        }
    }
}

// ---- K9: BN3 + residual + ReLU (float4) ------------------------------------
__global__ __launch_bounds__(256) void k_final(const float* __restrict__ y3,
        const float* __restrict__ x, float* __restrict__ out, const float* __restrict__ st) {
    int idx = blockIdx.x * 256 + threadIdx.x;   // float4 index
    if (idx < 1605632) {
        int c = (idx / 784) & 255;
        float a = st[FIN3 + c], bb = st[FIN3 + 256 + c];
        float4 v  = ((const float4*)y3)[idx];
        float4 xv = ((const float4*)x)[idx];
        float4 o;
        o.x = fmaxf(a * v.x + bb + xv.x, 0.f);
        o.y = fmaxf(a * v.y + bb + xv.y, 0.f);
        o.z = fmaxf(a * v.z + bb + xv.z, 0.f);
        o.w = fmaxf(a * v.w + bb + xv.w, 0.f);
        ((float4*)out)[idx] = o;
    }
}

extern "C" void kernel_launch(void* const* d_in, const int* in_sizes, int n_in,
                              void* d_out, int out_size, void* d_ws, size_t ws_size,
                              hipStream_t stream) {
    const float* x   = (const float*)d_in[0];
    const float* w1  = (const float*)d_in[1];
    const float* g1  = (const float*)d_in[2];
    const float* b1  = (const float*)d_in[3];
    const float* wr  = (const float*)d_in[4];
    const float* gr  = (const float*)d_in[5];
    const float* br  = (const float*)d_in[6];
    const float* wsp = (const float*)d_in[7];
    const float* g2  = (const float*)d_in[8];
    const float* b2  = (const float*)d_in[9];
    const float* w3  = (const float*)d_in[10];
    const float* g3  = (const float*)d_in[11];
    const float* b3  = (const float*)d_in[12];
    float* out = (float*)d_out;
    float* w   = (float*)d_ws;
    float* y1   = w + OFF_Y1;
    float* tr   = w + OFF_TR;
    float* w1t  = w + OFF_WT;
    float* w3t  = w + OFF_WT + 16384;
    float* out2 = w + OFF_OUT2;
    float* y3   = w + OFF_Y3;
    float* st   = w + OFF_ST;

    hipMemsetAsync(st, 0, 2048 * sizeof(float), stream);
    k_wt<<<128, 256, 0, stream>>>(w1, w3, w1t, w3t);
    k_conv1<<<784, 128, 0, stream>>>(x, w1t, y1, st);
    k_fin<<<1, 64, 0, stream>>>(st + ACC1, st + FIN1, g1, b1, 64);
    k_bn1_convr<<<NBLK, 256, 0, stream>>>(y1, wr, tr, st);
    k_fin<<<1, 64, 0, stream>>>(st + ACCR, st + FINR, gr, br, 16);
    k_invol<<<896, 256, 0, stream>>>(y1, tr, wsp, out2, st);
    k_fin<<<1, 64, 0, stream>>>(st + ACC2, st + FIN2, g2, b2, 64);
    k_bn2_conv3<<<NBLK * 4, 256, 0, stream>>>(out2, w3t, y3, st);
    k_fin<<<1, 256, 0, stream>>>(st + ACC3, st + FIN3, g3, b3, 256);
    k_final<<<6272, 256, 0, stream>>>(y3, x, out, st);
}

// Round 8
// 326.743 us; speedup vs baseline: 1.0161x; 1.0161x over previous
//
#include <hip/hip_runtime.h>

#define HW 3136          // 56*56
#define NPIX 25088       // 8*3136
#define NBLK 392         // NPIX/64

// workspace float offsets
#define OFF_Y1   0u
#define OFF_TR   1605632u
#define OFF_WT   2007040u      // w1t (16384) + w3t (16384)
#define OFF_OUT2 6924288u
#define OFF_Y3   8529920u
#define OFF_ST   14952448u
// stats sub-offsets (floats, relative to st base). acc: [C]=sum, [C..2C)=sumsq
#define ACC1 0
#define ACCR 128
#define ACC2 160
#define ACC3 288
#define FIN1 800
#define FINR 928
#define FIN2 960
#define FIN3 1088

__device__ __forceinline__ float wave_sum(float v) {
    #pragma unroll
    for (int off = 32; off > 0; off >>= 1) v += __shfl_xor(v, off, 64);
    return v;
}

// ---- K0: transpose weights w1[64][256]->w1t[256][64], w3[256][64]->w3t[64][256]
__global__ __launch_bounds__(256) void k_wt(const float* __restrict__ w1,
        const float* __restrict__ w3, float* __restrict__ w1t, float* __restrict__ w3t) {
    int i = blockIdx.x * 256 + threadIdx.x;
    if (i < 16384) {
        int oc = i >> 8, ic = i & 255;
        w1t[ic * 64 + oc] = w1[i];
    } else {
        int j = i - 16384;
        int oc = j >> 6, ic = j & 63;
        w3t[ic * 256 + oc] = w3[j];
    }
}

// ---- K1: conv1x1 256->64 + stats -------------------------------------------
// All weights resident in LDS (64KB, staged once); x streamed from global in a
// barrier-free K-loop. 64pix x 64oc per block, thread tile 4x4.
__global__ __launch_bounds__(256) void k_conv1(const float* __restrict__ x,
        const float* __restrict__ w1t, float* __restrict__ y1, float* __restrict__ st) {
    __shared__ float ws[256][64];   // [ic][oc] 64KB
    int t = threadIdx.x, pb = blockIdx.x;
    int b = pb / 49, hw0 = (pb % 49) * 64;
    int tx = t & 15, ty = t >> 4;   // pix group (4 pix) / oc quad
    #pragma unroll
    for (int i = 0; i < 16; i++) {
        int e = i * 256 + t;        // float4 index in [0,4096)
        int ic = e >> 4, q = e & 15;
        *(float4*)&ws[ic][q * 4] = *(const float4*)&w1t[ic * 64 + q * 4];
    }
    __syncthreads();
    float acc[4][4];
    #pragma unroll
    for (int i = 0; i < 4; i++)
        #pragma unroll
        for (int j = 0; j < 4; j++) acc[i][j] = 0.f;
    const float* xp = x + (size_t)(b * 256) * HW + hw0 + tx * 4;
    #pragma unroll 8
    for (int ic = 0; ic < 256; ic++) {
        float4 xv = *(const float4*)(xp + (size_t)ic * HW);
        float4 wv = *(const float4*)&ws[ic][ty * 4];
        float xa[4] = {xv.x, xv.y, xv.z, xv.w};
        float wa[4] = {wv.x, wv.y, wv.z, wv.w};
        #pragma unroll
        for (int i = 0; i < 4; i++)
            #pragma unroll
            for (int j = 0; j < 4; j++) acc[i][j] = fmaf(wa[i], xa[j], acc[i][j]);
    }
    #pragma unroll
    for (int i = 0; i < 4; i++) {
        int oc = ty * 4 + i;
        float4 o = make_float4(acc[i][0], acc[i][1], acc[i][2], acc[i][3]);
        *(float4*)&y1[((b * 64) + oc) * HW + hw0 + tx * 4] = o;
        float s = o.x + o.y + o.z + o.w;
        float q = o.x * o.x + o.y * o.y + o.z * o.z + o.w * o.w;
        #pragma unroll
        for (int off = 1; off <= 8; off <<= 1) {   // reduce over 16 tx lanes
            s += __shfl_xor(s, off, 64);
            q += __shfl_xor(q, off, 64);
        }
        if (tx == 0) {
            atomicAdd(&st[ACC1 + oc], s);
            atomicAdd(&st[ACC1 + 64 + oc], q);
        }
    }
}

// ---- finalize BN stats -> per-channel affine (a,b) -------------------------
__global__ void k_fin(const float* __restrict__ acc, float* __restrict__ fin,
                      const float* __restrict__ gamma, const float* __restrict__ beta, int C) {
    int c = threadIdx.x;
    if (c < C) {
        float mean = acc[c] * (1.0f / (float)NPIX);
        float var  = acc[C + c] * (1.0f / (float)NPIX) - mean * mean;
        float rstd = rsqrtf(var + 1e-5f);
        float a = gamma[c] * rstd;
        fin[c] = a;
        fin[C + c] = beta[c] - mean * a;
    }
}

// ---- K3: apply BN1+ReLU in-place, conv 64->16 + stats ----------------------
__global__ __launch_bounds__(256, 4) void k_bn1_convr(float* __restrict__ y1,
        const float* __restrict__ wr, float* __restrict__ tr, float* __restrict__ st) {
    __shared__ float ys[64][64];    // [ic][pix], BN1+ReLU applied
    __shared__ float wsh[16][64];   // [oc][ic]
    int t = threadIdx.x, pb = blockIdx.x;
    int b = pb / 49, hw0 = (pb % 49) * 64;
    int tx = t & 15, ty = t >> 4;   // pix group (4 pix) / oc (one of 16)
    #pragma unroll
    for (int i = 0; i < 16; i++) {
        int e = i * 256 + t, c = e >> 6, p = e & 63;
        int gi = ((b * 64) + c) * HW + hw0 + p;
        float v = y1[gi];
        v = fmaxf(st[FIN1 + c] * v + st[FIN1 + 64 + c], 0.f);
        ys[c][p] = v;
        y1[gi] = v;                 // y1 becomes y1r
    }
    #pragma unroll
    for (int i = 0; i < 4; i++) {
        int e = i * 256 + t;
        wsh[e >> 6][e & 63] = wr[e];
    }
    __syncthreads();
    float a0 = 0.f, a1 = 0.f, a2 = 0.f, a3 = 0.f;
    #pragma unroll 8
    for (int c = 0; c < 64; c++) {
        float4 yv = *(const float4*)&ys[c][tx * 4];
        float wv = wsh[ty][c];
        a0 = fmaf(wv, yv.x, a0); a1 = fmaf(wv, yv.y, a1);
        a2 = fmaf(wv, yv.z, a2); a3 = fmaf(wv, yv.w, a3);
    }
    *(float4*)&tr[((b * 16) + ty) * HW + hw0 + tx * 4] = make_float4(a0, a1, a2, a3);
    float s = a0 + a1 + a2 + a3;
    float q = a0 * a0 + a1 * a1 + a2 * a2 + a3 * a3;
    #pragma unroll
    for (int off = 1; off <= 8; off <<= 1) {
        s += __shfl_xor(s, off, 64);
        q += __shfl_xor(q, off, 64);
    }
    if (tx == 0) {
        atomicAdd(&st[ACCR + ty], s);
        atomicAdd(&st[ACCR + 16 + ty], q);
    }
}

// ---- K6: fused BNr+ReLU -> span conv (kernels in regs) -> involution + stats
// Split: each block handles 8 of the group's 16 channels (grid x2, LDS ~39KB).
__global__ __launch_bounds__(256) void k_invol(const float* __restrict__ y1r,
        const float* __restrict__ tr, const float* __restrict__ wsp,
        float* __restrict__ out2, float* __restrict__ st) {
    __shared__ float ts[16][256];      // BNr+ReLU'd tr tile (224 used)
    __shared__ float sw[49][16];       // span weights for this group
    __shared__ float ps[8][10][64];    // y1r halo tile (8 channels)
    __shared__ float red[4][16];
    int t = threadIdx.x, bidx = blockIdx.x;     // (((b*4+g)*14 + ht)*2 + h)
    int h = bidx & 1, r2 = bidx >> 1;
    int ht = r2 % 14;
    int bg = r2 / 14;
    int g = bg & 3, b = bg >> 2;
    int h0 = ht * 4;
    int c0 = h * 8;                    // channel offset within group
    // stage ts (BNr+ReLU applied) — all 16 channels (needed for kernel gen)
    #pragma unroll
    for (int i = 0; i < 16; i++) {
        int e = i * 256 + t, c = e >> 8, p = e & 255;
        if (p < 224) {
            float v = tr[((b * 16) + c) * HW + h0 * 56 + p];
            ts[c][p] = fmaxf(st[FINR + c] * v + st[FINR + 16 + c], 0.f);
        }
    }
    // stage span weights (group g): contiguous 784 floats
    for (int e = t; e < 784; e += 256) sw[e >> 4][e & 15] = wsp[g * 784 + e];
    // stage y1r halo for this block's 8 channels
    for (int i = 0; i < 20; i++) {
        int e = i * 256 + t;
        int c = e / 640, rem = e - c * 640;
        int r = rem >> 6, wc = rem & 63;
        int gh = h0 + r - 3, gw = wc - 3;
        float v = 0.f;
        if (gh >= 0 && gh < 56 && gw >= 0 && gw < 56)
            v = y1r[((b * 64) + g * 16 + c0 + c) * HW + gh * 56 + gw];
        ps[c][r][wc] = v;
    }
    __syncthreads();
    float accv[8];
    #pragma unroll
    for (int c = 0; c < 8; c++) accv[c] = 0.f;
    bool active = t < 224;
    if (active) {
        int lh = t / 56, lw = t % 56;
        // per-pixel kernel generation into registers (uses all 16 channels)
        float tsr[16];
        #pragma unroll
        for (int c = 0; c < 16; c++) tsr[c] = ts[c][t];
        float kr[49];
        #pragma unroll
        for (int k = 0; k < 49; k++) {
            const float4* swr = (const float4*)&sw[k][0];
            float4 u0 = swr[0], u1 = swr[1], u2 = swr[2], u3 = swr[3];
            float v = u0.x * tsr[0];
            v = fmaf(u0.y, tsr[1], v);  v = fmaf(u0.z, tsr[2], v);  v = fmaf(u0.w, tsr[3], v);
            v = fmaf(u1.x, tsr[4], v);  v = fmaf(u1.y, tsr[5], v);  v = fmaf(u1.z, tsr[6], v);
            v = fmaf(u1.w, tsr[7], v);  v = fmaf(u2.x, tsr[8], v);  v = fmaf(u2.y, tsr[9], v);
            v = fmaf(u2.z, tsr[10], v); v = fmaf(u2.w, tsr[11], v); v = fmaf(u3.x, tsr[12], v);
            v = fmaf(u3.y, tsr[13], v); v = fmaf(u3.z, tsr[14], v); v = fmaf(u3.w, tsr[15], v);
            kr[k] = v;
        }
        // involution MAC over this block's 8 channels
        #pragma unroll
        for (int k = 0; k < 49; k++) {
            int ki = k / 7, kj = k % 7;
            float kv = kr[k];
            #pragma unroll
            for (int c = 0; c < 8; c++)
                accv[c] = fmaf(kv, ps[c][lh + ki][lw + kj], accv[c]);
        }
        int hw = h0 * 56 + t;
        #pragma unroll
        for (int c = 0; c < 8; c++)
            out2[((b * 64) + g * 16 + c0 + c) * HW + hw] = accv[c];
    }
    int wave = t >> 6, lane = t & 63;
    #pragma unroll
    for (int c = 0; c < 8; c++) {
        float v = active ? accv[c] : 0.f;
        float s  = wave_sum(v);
        float s2 = wave_sum(v * v);
        if (lane == 0) { red[wave][c] = s; red[wave][8 + c] = s2; }
    }
    __syncthreads();
    if (t < 16) {
        float s = red[0][t] + red[1][t] + red[2][t] + red[3][t];
        int c = t & 7, isq = t >> 3;
        atomicAdd(&st[ACC2 + isq * 64 + g * 16 + c0 + c], s);
    }
}

// ---- K7: apply BN2+ReLU, conv 64->256 + stats ------------------------------
// Weight half (64x128 = 32KB) resident in LDS; out2 streamed from global with
// BN2+ReLU applied on read. Barrier-free K-loop. Thread tile 4pix x 8oc.
__global__ __launch_bounds__(256) void k_bn2_conv3(const float* __restrict__ out2,
        const float* __restrict__ w3t, float* __restrict__ y3, float* __restrict__ st) {
    __shared__ float ws[64][128];   // [ic][oc-half] 32KB
    int t = threadIdx.x, blk = blockIdx.x;
    int oh = blk & 1, pb = blk >> 1;
    int b = pb / 49, hw0 = (pb % 49) * 64;
    int tx = t & 15, ty = t >> 4;   // pix group (4 pix) / oc octet
    #pragma unroll
    for (int i = 0; i < 8; i++) {
        int e = i * 256 + t;        // float4 index in [0,2048)
        int ic = e >> 5, q = e & 31;
        *(float4*)&ws[ic][q * 4] = *(const float4*)&w3t[ic * 256 + oh * 128 + q * 4];
    }
    __syncthreads();
    float acc[8][4];
    #pragma unroll
    for (int i = 0; i < 8; i++)
        #pragma unroll
        for (int j = 0; j < 4; j++) acc[i][j] = 0.f;
    const float* xp = out2 + (size_t)(b * 64) * HW + hw0 + tx * 4;
    #pragma unroll 8
    for (int ic = 0; ic < 64; ic++) {
        float4 xv = *(const float4*)(xp + (size_t)ic * HW);
        float fa = st[FIN2 + ic], fb = st[FIN2 + 64 + ic];
        float xa[4];
        xa[0] = fmaxf(fmaf(fa, xv.x, fb), 0.f);
        xa[1] = fmaxf(fmaf(fa, xv.y, fb), 0.f);
        xa[2] = fmaxf(fmaf(fa, xv.z, fb), 0.f);
        xa[3] = fmaxf(fmaf(fa, xv.w, fb), 0.f);
        float4 wv0 = *(const float4*)&ws[ic][ty * 8];
        float4 wv1 = *(const float4*)&ws[ic][ty * 8 + 4];
        float wa[8] = {wv0.x, wv0.y, wv0.z, wv0.w, wv1.x, wv1.y, wv1.z, wv1.w};
        #pragma unroll
        for (int i = 0; i < 8; i++)
            #pragma unroll
            for (int j = 0; j < 4; j++) acc[i][j] = fmaf(wa[i], xa[j], acc[i][j]);
    }
    #pragma unroll
    for (int i = 0; i < 8; i++) {
        int oc = oh * 128 + ty * 8 + i;
        float4 o = make_float4(acc[i][0], acc[i][1], acc[i][2], acc[i][3]);
        *(float4*)&y3[((b * 256) + oc) * HW + hw0 + tx * 4] = o;
        float s = o.x + o.y + o.z + o.w;
        float q = o.x * o.x + o.y * o.y + o.z * o.z + o.w * o.w;
        #pragma unroll
        for (int off = 1; off <= 8; off <<= 1) {   // reduce over 16 tx lanes
            s += __shfl_xor(s, off, 64);
            q += __shfl_xor(q, off, 64);
        }
        if (tx == 0) {
            atomicAdd(&st[ACC3 + oc], s);
            atomicAdd(&st[ACC3 + 256 + oc], q);
        }
    }
}

// ---- K9: BN3 + residual + ReLU (float4) ------------------------------------
__global__ __launch_bounds__(256) void k_final(const float* __restrict__ y3,
        const float* __restrict__ x, float* __restrict__ out, const float* __restrict__ st) {
    int idx = blockIdx.x * 256 + threadIdx.x;   // float4 index
    if (idx < 1605632) {
        int c = (idx / 784) & 255;
        float a = st[FIN3 + c], bb = st[FIN3 + 256 + c];
        float4 v  = ((const float4*)y3)[idx];
        float4 xv = ((const float4*)x)[idx];
        float4 o;
        o.x = fmaxf(a * v.x + bb + xv.x, 0.f);
        o.y = fmaxf(a * v.y + bb + xv.y, 0.f);
        o.z = fmaxf(a * v.z + bb + xv.z, 0.f);
        o.w = fmaxf(a * v.w + bb + xv.w, 0.f);
        ((float4*)out)[idx] = o;
    }
}

extern "C" void kernel_launch(void* const* d_in, const int* in_sizes, int n_in,
                              void* d_out, int out_size, void* d_ws, size_t ws_size,
                              hipStream_t stream) {
    const float* x   = (const float*)d_in[0];
    const float* w1  = (const float*)d_in[1];
    const float* g1  = (const float*)d_in[2];
    const float* b1  = (const float*)d_in[3];
    const float* wr  = (const float*)d_in[4];
    const float* gr  = (const float*)d_in[5];
    const float* br  = (const float*)d_in[6];
    const float* wsp = (const float*)d_in[7];
    const float* g2  = (const float*)d_in[8];
    const float* b2  = (const float*)d_in[9];
    const float* w3  = (const float*)d_in[10];
    const float* g3  = (const float*)d_in[11];
    const float* b3  = (const float*)d_in[12];
    float* out = (float*)d_out;
    float* w   = (float*)d_ws;
    float* y1   = w + OFF_Y1;
    float* tr   = w + OFF_TR;
    float* w1t  = w + OFF_WT;
    float* w3t  = w + OFF_WT + 16384;
    float* out2 = w + OFF_OUT2;
    float* y3   = w + OFF_Y3;
    float* st   = w + OFF_ST;

    hipMemsetAsync(st, 0, 2048 * sizeof(float), stream);
    k_wt<<<128, 256, 0, stream>>>(w1, w3, w1t, w3t);
    k_conv1<<<NBLK, 256, 0, stream>>>(x, w1t, y1, st);
    k_fin<<<1, 64, 0, stream>>>(st + ACC1, st + FIN1, g1, b1, 64);
    k_bn1_convr<<<NBLK, 256, 0, stream>>>(y1, wr, tr, st);
    k_fin<<<1, 64, 0, stream>>>(st + ACCR, st + FINR, gr, br, 16);
    k_invol<<<896, 256, 0, stream>>>(y1, tr, wsp, out2, st);
    k_fin<<<1, 64, 0, stream>>>(st + ACC2, st + FIN2, g2, b2, 64);
    k_bn2_conv3<<<NBLK * 2, 256, 0, stream>>>(out2, w3t, y3, st);
    k_fin<<<1, 256, 0, stream>>>(st + ACC3, st + FIN3, g3, b3, 256);
    k_final<<<6272, 256, 0, stream>>>(y3, x, out, st);
}